// Round 9
// baseline (51.249 us; speedup 1.0000x reference)
//
#include <hip/hip_runtime.h>
#include <math.h>

#define N_PART 50000
#define KMAX 80
#define KS 4
#define NTOT (N_PART * KMAX)   // 4,000,000 = 15625 * 256

typedef __attribute__((ext_vector_type(8))) _Float16 h8;
typedef __attribute__((ext_vector_type(2))) _Float16 h2;

// minimax odd polynomial for atan(t), t in [-1,1]; max abs err ~1e-5
__device__ __forceinline__ float atan_poly(float t) {
    float t2 = t * t;
    float p = -0.01172120f;
    p = p * t2 + 0.05265332f;
    p = p * t2 - 0.11643287f;
    p = p * t2 + 0.19354346f;
    p = p * t2 - 0.33262347f;
    p = p * t2 + 0.99997726f;
    return t * p;
}

__global__ __launch_bounds__(256) void zero_out_kernel(float* __restrict__ out, int n) {
    int i = blockIdx.x * blockDim.x + threadIdx.x;
    if (i < n) out[i] = 0.0f;
}

__global__ __launch_bounds__(256) void cconv_pair_kernel(
    const float* __restrict__ pos,
    const float* __restrict__ vel,
    const float* __restrict__ Wg,      // [64*3*3] (g, cin, cout)
    const int* __restrict__ nidx,      // [N][KMAX]
    const void* __restrict__ nmask,    // [N][KMAX], dtype detected per-wave
    float* __restrict__ out)           // [N][3], pre-zeroed; atomic accumulate
{
    // W[c][0..7] as fp16 (one ds_read_b128/corner), W[c][8] as f32.
    __shared__ _Float16 WsH[64 * 8];
    __shared__ float    Ws8[64];
    for (int t = threadIdx.x; t < 64 * 8; t += blockDim.x) {
        int g = t >> 3, r = t & 7;
        WsH[t] = (_Float16)Wg[g * 9 + r];
    }
    for (int t = threadIdx.x; t < 64; t += blockDim.x)
        Ws8[t] = Wg[t * 9 + 8];
    __syncthreads();

    int t = blockIdx.x * blockDim.x + threadIdx.x;   // pair id, < NTOT exactly
    unsigned tu = (unsigned)t;
    int p    = (int)(tu / 80u);        // particle  (magic-mul)
    int lane = threadIdx.x & 63;

    // ---- per-wave mask-dtype detection (int32 vs byte-bool storage) ----
    bool byteMask;
    {
        const unsigned* mw = (const unsigned*)nmask;
        bool big = false;
        #pragma unroll
        for (int i = 0; i < 8; ++i)
            big |= (mw[lane + 64 * i] > 1u);
        byteMask = (__ballot(big) != 0ULL);
    }

    // ---- this pair's validity (flat; no prefix assumption needed) ----
    bool valid;
    if (byteMask) valid = ((const unsigned char*)nmask)[t] != 0;
    else          valid = ((const int*)nmask)[t] != 0;

    // whole-wave early exit: all 64 slots masked
    if (__ballot(valid) == 0ULL) return;

    int   idx  = nidx[t];              // 0 for padded slots -> safe gather
    float vmsk = valid ? 1.0f : 0.0f;

    const float inv_r = 1.0f / 0.3f;
    const float eps   = 1e-12f;
    const float FOUR_OVER_PI = 1.27323954473516268615f;

    float cpx = pos[3 * p], cpy = pos[3 * p + 1], cpz = pos[3 * p + 2];
    float npx = pos[3 * idx], npy = pos[3 * idx + 1], npz = pos[3 * idx + 2];
    float ux  = vel[3 * idx], uy  = vel[3 * idx + 1], uz  = vel[3 * idx + 2];

    float rx = (npx - cpx) * inv_r;
    float ry = (npy - cpy) * inv_r;
    float rz = (npz - cpz) * inv_r;

    float sq = rx * rx + ry * ry + rz * rz;

    // window_poly6 (vmask folded: masked pairs contribute exactly 0)
    float t1  = 1.0f - sq;
    float imp = fminf(fmaxf(t1 * t1 * t1, 0.0f), 1.0f) * vmsk;

    // ---- ball -> cylinder (volume preserving), branch-lite ----
    float norm  = sqrtf(fmaxf(sq, eps));
    float sq_xy = rx * rx + ry * ry;
    bool  top   = (1.25f * rz * rz) > sq_xy;
    float s_top  = sqrtf(3.0f * norm * __builtin_amdgcn_rcpf(norm + fabsf(rz)));
    float s_side = norm * __builtin_amdgcn_rsqf(fmaxf(sq_xy, eps));
    float s  = top ? s_top : s_side;
    float x1 = rx * s;
    float y1 = ry * s;
    float z1 = top ? copysignf(norm, rz) : 1.5f * rz;
    if (sq < eps) { x1 = rx; y1 = ry; z1 = rz; }

    // ---- cylinder -> cube (equal-area disc -> square) ----
    float sq1 = x1 * x1 + y1 * y1;
    float nxy = sqrtf(fmaxf(sq1, eps));
    bool  xb  = fabsf(y1) <= fabsf(x1);
    float num = xb ? y1 : x1;
    float den = xb ? x1 : y1;
    float sden = (fabsf(den) > eps) ? den : 1.0f;
    float tt   = num * __builtin_amdgcn_rcpf(sden);
    float at   = atan_poly(tt);
    float sd   = copysignf(nxy, den);
    float u    = sd * FOUR_OVER_PI * at;
    float x2   = xb ? sd : u;
    float y2   = xb ? u  : sd;
    if (sq1 < eps) { x2 = x1; y2 = y1; }

    // ---- trilinear grid coords, align_corners=True, clamped ----
    float tx = fminf(fmaxf((x2 + 1.0f) * 1.5f, 0.0f), 3.0f);
    float ty = fminf(fmaxf((y2 + 1.0f) * 1.5f, 0.0f), 3.0f);
    float tz = fminf(fmaxf((z1 + 1.0f) * 1.5f, 0.0f), 3.0f);
    float fx0 = floorf(tx), fy0 = floorf(ty), fz0 = floorf(tz);
    int xi0 = (int)fx0, yi0 = (int)fy0, zi0 = (int)fz0;
    int xi1 = min(xi0 + 1, KS - 1);
    int yi1 = min(yi0 + 1, KS - 1);
    int zi1 = min(zi0 + 1, KS - 1);
    float wx1 = tx - fx0, wx0 = 1.0f - wx1;
    float wy1 = ty - fy0, wy0 = 1.0f - wy1;
    float wz1 = tz - fz0, wz0 = 1.0f - wz1;

    int   zia[2] = { zi0, zi1 };  float wza[2] = { wz0, wz1 };
    int   yia[2] = { yi0, yi1 };  float wya[2] = { wy0, wy1 };
    int   xia[2] = { xi0, xi1 };  float wxa[2] = { wx0, wx1 };

    // ---- per-pair M = sum_c w_c * W_c, accumulated in packed fp16 ----
    h2 M01 = (h2)(_Float16)0.0f;
    h2 M23 = (h2)(_Float16)0.0f;
    h2 M45 = (h2)(_Float16)0.0f;
    h2 M67 = (h2)(_Float16)0.0f;
    float m8 = 0.0f;

    #pragma unroll
    for (int cz = 0; cz < 2; ++cz) {
        #pragma unroll
        for (int cy = 0; cy < 2; ++cy) {
            float wzy = wza[cz] * wya[cy];
            #pragma unroll
            for (int cx = 0; cx < 2; ++cx) {
                int corner = (zia[cz] * KS + yia[cy]) * KS + xia[cx];
                h8 wv = *(const h8*)&WsH[corner << 3];   // ds_read_b128
                float wf = wzy * wxa[cx];
                _Float16 wh = (_Float16)wf;
                h2 ww = { wh, wh };
                M01 += ww * __builtin_shufflevector(wv, wv, 0, 1);
                M23 += ww * __builtin_shufflevector(wv, wv, 2, 3);
                M45 += ww * __builtin_shufflevector(wv, wv, 4, 5);
                M67 += ww * __builtin_shufflevector(wv, wv, 6, 7);
                m8  += wf * Ws8[corner];                 // ds_read_b32
            }
        }
    }

    float m0 = (float)M01[0], m1 = (float)M01[1];
    float m2 = (float)M23[0], m3 = (float)M23[1];
    float m4 = (float)M45[0], m5 = (float)M45[1];
    float m6 = (float)M67[0], m7 = (float)M67[1];
    float v0 = imp * (ux * m0 + uy * m3 + uz * m6);
    float v1 = imp * (ux * m1 + uy * m4 + uz * m7);
    float v2 = imp * (ux * m2 + uy * m5 + uz * m8);

    // ---- in-wave segmented inclusive scan over contiguous equal-p runs ----
    #pragma unroll
    for (int d = 1; d < 64; d <<= 1) {
        int src = lane - d;
        int cs  = max(src, 0);
        int   pp = __shfl(p,  cs, 64);
        float f0 = __shfl(v0, cs, 64);
        float f1 = __shfl(v1, cs, 64);
        float f2 = __shfl(v2, cs, 64);
        bool take = (src >= 0) && (pp == p);
        v0 += take ? f0 : 0.0f;
        v1 += take ? f1 : 0.0f;
        v2 += take ? f2 : 0.0f;
    }

    // last lane of each segment owns the partial sum for its particle
    int  nl = min(lane + 1, 63);
    int  pn = __shfl(p, nl, 64);
    bool lastInSeg = (lane == 63) || (pn != p);
    if (lastInSeg) {
        atomicAdd(&out[3 * p + 0], v0);
        atomicAdd(&out[3 * p + 1], v1);
        atomicAdd(&out[3 * p + 2], v2);
    }
}

extern "C" void kernel_launch(void* const* d_in, const int* in_sizes, int n_in,
                              void* d_out, int out_size, void* d_ws, size_t ws_size,
                              hipStream_t stream) {
    const float* pos   = (const float*)d_in[0];
    const float* vel   = (const float*)d_in[1];
    const float* Wg    = (const float*)d_in[2];
    const int*   nidx  = (const int*)d_in[3];
    const void*  nmask = d_in[4];
    float*       out   = (float*)d_out;

    int nOut = out_size;   // 150000
    zero_out_kernel<<<(nOut + 255) / 256, 256, 0, stream>>>(out, nOut);

    int threads = 256;
    int grid    = NTOT / threads;      // 15625, exact
    cconv_pair_kernel<<<grid, threads, 0, stream>>>(pos, vel, Wg, nidx, nmask, out);
}